// Round 8
// baseline (64.815 us; speedup 1.0000x reference)
//
#include <hip/hip_runtime.h>
#include <math.h>

constexpr int B = 16, H = 16, KVH = 4, D = 128;
constexpr int BLK = 16, MAXB = 256;
constexpr int GRP = H / KVH;   // 4 query heads per KV head
constexpr int NSL = 16;        // slices per (b,hkv)
constexpr int NE  = NSL * 4;   // 64 wave-partials per group
constexpr int WSTRIDE = D + 2; // partial: o[128], m, s
constexpr int ESTRIDE = GRP * WSTRIDE;  // 520 floats per wave-entry

// Layout closed form (verified R7): head h attends kb iff pbid-kb<32 or kb%8==h%8.
// Group hkv: phases p..p+3, p=(hkv&1)*4. Union = strided [0,M) (kb monotone,
// prefix-valid: kb=8*(i>>2)+p+(i&3), mask=1<<(i&3)) + local [M,pbid] (mask 15).

__global__ __launch_bounds__(256) void sparse_attn_online(
    const float* __restrict__ q,            // (B,H,D)
    const float* __restrict__ k_cache,      // (NB,KVH,32,16,4)
    const float* __restrict__ v_cache,      // (NB,KVH,128,16)
    const int* __restrict__ block_tables,   // (B,MAXB)
    const int* __restrict__ context_lens,   // (B,)
    float* __restrict__ ws)
{
    const int wg = blockIdx.x;
    const int gidx = wg >> 4;               // b*KVH + hkv
    const int slice = wg & (NSL - 1);
    const int b = gidx >> 2, hkv = gidx & 3;
    const int tid = threadIdx.x;
    const int lane = tid & 63;
    const int wv = tid >> 6;                // 0..3

    const int q_pid = context_lens[b] - 1;
    const int pbid = q_pid >> 4;
    const int p = (hkv & 1) * 4;
    const int M = max(0, pbid - 31);        // strided region = [0, M)
    int nstr = 0;
    #pragma unroll
    for (int u = 0; u < 4; ++u) {
        const int dd = M - p - u;
        nstr += (dd > 0) ? ((dd + 7) >> 3) : 0;
    }
    const int U = nstr + (pbid - M + 1);

    __shared__ float s_q[GRP * D];          // 2 KB
    __shared__ float s_p[4][GRP][BLK];      // 1 KB, wave-private by wv

    for (int i = tid; i < GRP * D; i += 256)
        s_q[i] = q[(b * H + hkv * GRP + (i >> 7)) * D + (i & 127)];
    __syncthreads();                        // the only barrier
    const float4* q4 = (const float4*)s_q;

    const float sm_scale = 0.08838834764831845f; // 1/sqrt(128)
    const int n  = (lane >> 2) & 15;        // token
    const int dq = lane & 3;                // dim-quarter

    float m[GRP], s[GRP], o0[GRP], o1[GRP]; // online state; lane owns d=2*lane, 2*lane+1
    #pragma unroll
    for (int g = 0; g < GRP; ++g) { m[g] = -INFINITY; s[g] = 0.f; o0[g] = 0.f; o1[g] = 0.f; }

    // wave wv of slice handles union indices slice + (wv+4t)*NSL
    for (int iu = slice + wv * NSL; iu < U; iu += 4 * NSL) {
        int kb, mk;
        if (iu < nstr) { kb = ((iu >> 2) << 3) + p + (iu & 3); mk = 1 << (iu & 3); }
        else           { kb = M + (iu - nstr);                 mk = 15; }
        const int bt = block_tables[b * MAXB + kb];   // wave-uniform scalar load
        const float4* kp = (const float4*)(k_cache + (size_t)(bt * KVH + hkv) * (D * BLK));
        const float4* vp = (const float4*)(v_cache + (size_t)(bt * KVH + hkv) * (D * BLK));

        // issue ALL loads for this block up front (16 x 16B per lane in flight)
        float4 vbuf[8];                      // rows d=2*lane, 2*lane+1 of V block
        #pragma unroll
        for (int i = 0; i < 8; ++i) vbuf[i] = vp[lane * 8 + i];

        const int pos = kb * BLK + n;
        float acc[GRP] = {0.f, 0.f, 0.f, 0.f};
        #pragma unroll
        for (int i = 0; i < 8; ++i) {
            const int d1 = dq * 8 + i;
            const float4 kv = kp[d1 * 16 + n];
            #pragma unroll
            for (int g = 0; g < GRP; ++g) {
                const float4 qv = q4[g * 32 + d1];
                acc[g] += kv.x * qv.x + kv.y * qv.y + kv.z * qv.z + kv.w * qv.w;
            }
        }

        #pragma unroll
        for (int g = 0; g < GRP; ++g) {
            float a = acc[g];
            a += __shfl_xor(a, 1);
            a += __shfl_xor(a, 2);           // full dot on all 4 dq lanes
            const float sc = (((mk >> g) & 1) && pos <= q_pid) ? a * sm_scale : -INFINITY;
            float bm = sc;
            #pragma unroll
            for (int off = 4; off < 64; off <<= 1)
                bm = fmaxf(bm, __shfl_xor(bm, off));   // max over tokens
            const float mn = fmaxf(m[g], bm);
            const float f = (m[g] == mn) ? 1.f : __expf(m[g] - mn);  // -inf==-inf safe
            const float pg = (sc == -INFINITY) ? 0.f : __expf(sc - mn);
            float ps = pg;
            #pragma unroll
            for (int off = 4; off < 64; off <<= 1)
                ps += __shfl_xor(ps, off);
            s[g] = s[g] * f + ps;
            o0[g] *= f; o1[g] *= f;
            m[g] = mn;
            if (dq == 0) s_p[wv][g][n] = pg; // wave-private, no barrier needed
        }

        // PV: lane's rows d=2*lane (vbuf[0..3]), d=2*lane+1 (vbuf[4..7])
        #pragma unroll
        for (int g = 0; g < GRP; ++g) {
            const float4* pp = (const float4*)s_p[wv][g];
            const float4 p0 = pp[0], p1 = pp[1], p2 = pp[2], p3 = pp[3];
            o0[g] += vbuf[0].x*p0.x + vbuf[0].y*p0.y + vbuf[0].z*p0.z + vbuf[0].w*p0.w
                   + vbuf[1].x*p1.x + vbuf[1].y*p1.y + vbuf[1].z*p1.z + vbuf[1].w*p1.w
                   + vbuf[2].x*p2.x + vbuf[2].y*p2.y + vbuf[2].z*p2.z + vbuf[2].w*p2.w
                   + vbuf[3].x*p3.x + vbuf[3].y*p3.y + vbuf[3].z*p3.z + vbuf[3].w*p3.w;
            o1[g] += vbuf[4].x*p0.x + vbuf[4].y*p0.y + vbuf[4].z*p0.z + vbuf[4].w*p0.w
                   + vbuf[5].x*p1.x + vbuf[5].y*p1.y + vbuf[5].z*p1.z + vbuf[5].w*p1.w
                   + vbuf[6].x*p2.x + vbuf[6].y*p2.y + vbuf[6].z*p2.z + vbuf[6].w*p2.w
                   + vbuf[7].x*p3.x + vbuf[7].y*p3.y + vbuf[7].z*p3.z + vbuf[7].w*p3.w;
        }
    }

    // write wave-partial (entry wg*4+wv = gidx*64 + slice*4 + wv)
    float* pb = ws + (size_t)(wg * 4 + wv) * ESTRIDE;
    #pragma unroll
    for (int g = 0; g < GRP; ++g) {
        pb[g * WSTRIDE + 2 * lane]     = o0[g];
        pb[g * WSTRIDE + 2 * lane + 1] = o1[g];
    }
    if (lane == 0) {
        #pragma unroll
        for (int g = 0; g < GRP; ++g) {
            pb[g * WSTRIDE + D]     = m[g];
            pb[g * WSTRIDE + D + 1] = s[g];
        }
    }
}

// ---------------- combine: LSE-merge 64 wave-partials per (b,h) ----------------
__global__ __launch_bounds__(128) void sparse_attn_combine(
    const float* __restrict__ ws,
    float* __restrict__ out)
{
    const int bh = blockIdx.x;              // b*H + h
    const int h = bh & (H - 1), b = bh >> 4;
    const int gidx = b * 4 + (h >> 2);
    const int g = h & 3;
    const int d = threadIdx.x;

    const float* base = ws + (size_t)gidx * NE * ESTRIDE + g * WSTRIDE;

    float m = -INFINITY;
    #pragma unroll 8
    for (int e = 0; e < NE; ++e)
        m = fmaxf(m, base[(size_t)e * ESTRIDE + D]);

    float num = 0.f, den = 0.f;
    #pragma unroll 4
    for (int e = 0; e < NE; ++e) {
        const float ms = base[(size_t)e * ESTRIDE + D];
        const float ss = base[(size_t)e * ESTRIDE + D + 1];
        const float a = (ms == -INFINITY) ? 0.f : __expf(ms - m);
        num += base[(size_t)e * ESTRIDE + d] * a;
        den += ss * a;
    }
    out[bh * D + d] = num / den;
}

extern "C" void kernel_launch(void* const* d_in, const int* in_sizes, int n_in,
                              void* d_out, int out_size, void* d_ws, size_t ws_size,
                              hipStream_t stream) {
    const float* q            = (const float*)d_in[0];
    const float* k_cache      = (const float*)d_in[1];
    const float* v_cache      = (const float*)d_in[2];
    const int*   block_tables = (const int*)d_in[3];
    const int*   context_lens = (const int*)d_in[4];
    float* out = (float*)d_out;
    float* ws  = (float*)d_ws;

    sparse_attn_online<<<B * KVH * NSL, 256, 0, stream>>>(
        q, k_cache, v_cache, block_tables, context_lens, ws);
    sparse_attn_combine<<<B * H, 128, 0, stream>>>(ws, out);
}

// Round 9
// 50.700 us; speedup vs baseline: 1.2784x; 1.2784x over previous
//
#include <hip/hip_runtime.h>
#include <math.h>

constexpr int B = 16, H = 16, KVH = 4, D = 128;
constexpr int BLK = 16, MAXB = 256;
constexpr int GRP = H / KVH;     // 4 query heads per KV head
constexpr int NSL = 16;          // slices per (b,hkv); slice s owns union idx s, s+NSL, ...
constexpr int MAXCNT = 9;        // ceil(144/16)
constexpr int OSZ = GRP * D;     // 512
constexpr int WSTRIDE = OSZ + 2 * GRP;  // o[4][128], m[4], s[4] = 520 floats

// Layout closed form (verified R7): head h attends kb iff pbid-kb<32 or kb%8==h%8.
// Group hkv: phases p..p+3, p=(hkv&1)*4. Union = strided [0,M) prefix-valid
// (kb=8*(i>>2)+p+(i&3), mask=1<<(i&3)) + local [M,pbid] (mask 15).

__global__ __launch_bounds__(256, 4) void sparse_attn_slice(
    const float* __restrict__ q,            // (B,H,D)
    const float* __restrict__ k_cache,      // (NB,KVH,32,16,4)
    const float* __restrict__ v_cache,      // (NB,KVH,128,16)
    const int* __restrict__ block_tables,   // (B,MAXB)
    const int* __restrict__ context_lens,   // (B,)
    float* __restrict__ ws)
{
    const int wg = blockIdx.x;
    const int gidx = wg >> 4, slice = wg & (NSL - 1);
    const int b = gidx >> 2, hkv = gidx & 3;
    const int tid = threadIdx.x;
    const int lane = tid & 63;
    const int wv = tid >> 6;                // 0..3

    const int q_pid = context_lens[b] - 1;
    const int pbid = q_pid >> 4;
    const int p = (hkv & 1) * 4;
    const int M = max(0, pbid - 31);        // strided region = [0, M)
    int nstr = 0;
    #pragma unroll
    for (int u = 0; u < 4; ++u) {
        const int dd = M - p - u;
        nstr += (dd > 0) ? ((dd + 7) >> 3) : 0;
    }
    const int U = nstr + (pbid - M + 1);
    const int cnt = (slice < U) ? ((U - 1 - slice) / NSL + 1) : 0;   // <= 9

    float* pb = ws + (size_t)wg * WSTRIDE;
    if (cnt == 0) {                         // must still write (ws poisoned)
        for (int i = tid; i < WSTRIDE; i += 256)
            pb[i] = (i >= OSZ && i < OSZ + GRP) ? -INFINITY : 0.f;
        return;
    }

    __shared__ float s_q[GRP * D];              // 2 KB
    __shared__ float s_p[GRP][MAXCNT * BLK];    // raw scores then probs, 2.3 KB
    __shared__ int   s_col[MAXCNT], s_msk[MAXCNT], s_bt[MAXCNT];
    __shared__ float s_m[GRP], s_s[GRP];
    __shared__ float s_o[4][GRP * D];           // per-wave PV partials, 8 KB

    if (tid < 128)
        ((float4*)s_q)[tid] = ((const float4*)(q + (size_t)(b * H + hkv * GRP) * D))[tid];
    if (tid < cnt) {
        const int i = slice + tid * NSL;
        int kb, mk;
        if (i < nstr) { kb = ((i >> 2) << 3) + p + (i & 3); mk = 1 << (i & 3); }
        else          { kb = M + (i - nstr);                mk = 15; }
        s_col[tid] = kb;
        s_msk[tid] = mk;
        s_bt[tid]  = block_tables[b * MAXB + kb];
    }
    __syncthreads();

    const float sm_scale = 0.08838834764831845f; // 1/sqrt(128)
    const float4* q4 = (const float4*)s_q;

    // ---- scores: wave per block; whole 8KB K block in flight, instr-coalesced
    // lane = (dg, n): n = lane&15 (token), dg = lane>>4; f4 idx lane+64i -> d1 = dg+4i
    {
        const int n = lane & 15;
        const int dg = lane >> 4;
        for (int j = wv; j < cnt; j += 4) {
            const float4* kp = (const float4*)(k_cache + (size_t)(s_bt[j] * KVH + hkv) * (D * BLK));
            float4 kb4[8];
            #pragma unroll
            for (int i = 0; i < 8; ++i) kb4[i] = kp[lane + 64 * i];
            float acc[GRP] = {0.f, 0.f, 0.f, 0.f};
            #pragma unroll
            for (int i = 0; i < 8; ++i) {
                const int d1 = dg + 4 * i;
                const float4 kv = kb4[i];
                #pragma unroll
                for (int g = 0; g < GRP; ++g) {
                    const float4 qv = q4[g * 32 + d1];
                    acc[g] += kv.x * qv.x + kv.y * qv.y + kv.z * qv.z + kv.w * qv.w;
                }
            }
            #pragma unroll
            for (int g = 0; g < GRP; ++g) {
                float a = acc[g];
                a += __shfl_xor(a, 16);
                a += __shfl_xor(a, 32);      // sum over the 4 dg groups
                if (dg == 0) s_p[g][j * 16 + n] = a * sm_scale;  // raw, unmasked
            }
        }
    }
    __syncthreads();

    // ---- softmax: wave g owns head g; mask (head-phase + causal), max, exp, sum
    {
        const int g = wv;
        const int tot = cnt * 16;
        float vals[3];
        float mx = -INFINITY;
        #pragma unroll
        for (int t = 0; t < 3; ++t) {
            const int e = lane + 64 * t;
            float v = -INFINITY;
            if (e < tot) {
                const int j = e >> 4, nn = e & 15;
                const int pos = s_col[j] * BLK + nn;
                if (((s_msk[j] >> g) & 1) && pos <= q_pid) v = s_p[g][e];
            }
            vals[t] = v;
            mx = fmaxf(mx, v);
        }
        #pragma unroll
        for (int off = 1; off < 64; off <<= 1)
            mx = fmaxf(mx, __shfl_xor(mx, off));
        float sum = 0.f;
        #pragma unroll
        for (int t = 0; t < 3; ++t) {
            const int e = lane + 64 * t;
            const float pe = (vals[t] == -INFINITY) ? 0.f : __expf(vals[t] - mx);
            sum += pe;
            if (e < tot) s_p[g][e] = pe;
        }
        #pragma unroll
        for (int off = 1; off < 64; off <<= 1)
            sum += __shfl_xor(sum, off);
        if (lane == 0) { s_m[g] = mx; s_s[g] = sum; }
    }
    __syncthreads();

    // ---- PV: wave per block; whole 8KB V block in flight; lane owns rows 2l, 2l+1
    {
        float o0[GRP] = {0.f, 0.f, 0.f, 0.f};
        float o1[GRP] = {0.f, 0.f, 0.f, 0.f};
        for (int j = wv; j < cnt; j += 4) {
            const float4* vp = (const float4*)(v_cache + (size_t)(s_bt[j] * KVH + hkv) * (D * BLK));
            float4 vb4[8];
            #pragma unroll
            for (int i = 0; i < 8; ++i) vb4[i] = vp[lane * 8 + i];
            #pragma unroll
            for (int g = 0; g < GRP; ++g) {
                const float4* pp = (const float4*)&s_p[g][j * 16];
                const float4 p0 = pp[0], p1 = pp[1], p2 = pp[2], p3 = pp[3];
                o0[g] += vb4[0].x*p0.x + vb4[0].y*p0.y + vb4[0].z*p0.z + vb4[0].w*p0.w
                       + vb4[1].x*p1.x + vb4[1].y*p1.y + vb4[1].z*p1.z + vb4[1].w*p1.w
                       + vb4[2].x*p2.x + vb4[2].y*p2.y + vb4[2].z*p2.z + vb4[2].w*p2.w
                       + vb4[3].x*p3.x + vb4[3].y*p3.y + vb4[3].z*p3.z + vb4[3].w*p3.w;
                o1[g] += vb4[4].x*p0.x + vb4[4].y*p0.y + vb4[4].z*p0.z + vb4[4].w*p0.w
                       + vb4[5].x*p1.x + vb4[5].y*p1.y + vb4[5].z*p1.z + vb4[5].w*p1.w
                       + vb4[6].x*p2.x + vb4[6].y*p2.y + vb4[6].z*p2.z + vb4[6].w*p2.w
                       + vb4[7].x*p3.x + vb4[7].y*p3.y + vb4[7].z*p3.z + vb4[7].w*p3.w;
            }
        }
        #pragma unroll
        for (int g = 0; g < GRP; ++g) {
            float2* dst = (float2*)&s_o[wv][g * D + 2 * lane];
            *dst = make_float2(o0[g], o1[g]);
        }
    }
    __syncthreads();

    // ---- merge 4 wave-partials (plain add; softmax stats are global) + write
    {
        const int f = tid * 2;
        const float r0 = s_o[0][f] + s_o[1][f] + s_o[2][f] + s_o[3][f];
        const float r1 = s_o[0][f+1] + s_o[1][f+1] + s_o[2][f+1] + s_o[3][f+1];
        ((float2*)pb)[tid] = make_float2(r0, r1);
        if (tid < GRP) {
            pb[OSZ + tid]       = s_m[tid];
            pb[OSZ + GRP + tid] = s_s[tid];
        }
    }
}

// ---------------- combine: LSE-merge NSL slices per (b,h) ----------------
__global__ __launch_bounds__(128) void sparse_attn_combine(
    const float* __restrict__ ws,
    float* __restrict__ out)
{
    const int bh = blockIdx.x;              // b*H + h
    const int h = bh & (H - 1), b = bh >> 4;
    const int gidx = b * KVH + (h >> 2);
    const int g = h & 3;
    const int d = threadIdx.x;

    const float* base = ws + (size_t)(gidx * NSL) * WSTRIDE;

    float m = -INFINITY;
    #pragma unroll
    for (int e = 0; e < NSL; ++e)
        m = fmaxf(m, base[e * WSTRIDE + OSZ + g]);

    float num = 0.f, den = 0.f;
    #pragma unroll
    for (int e = 0; e < NSL; ++e) {
        const float ms = base[e * WSTRIDE + OSZ + g];
        const float ss = base[e * WSTRIDE + OSZ + GRP + g];
        const float a = (ms == -INFINITY) ? 0.f : __expf(ms - m);
        num += base[e * WSTRIDE + g * D + d] * a;
        den += ss * a;
    }
    out[bh * D + d] = num / den;
}

extern "C" void kernel_launch(void* const* d_in, const int* in_sizes, int n_in,
                              void* d_out, int out_size, void* d_ws, size_t ws_size,
                              hipStream_t stream) {
    const float* q            = (const float*)d_in[0];
    const float* k_cache      = (const float*)d_in[1];
    const float* v_cache      = (const float*)d_in[2];
    const int*   block_tables = (const int*)d_in[3];
    const int*   context_lens = (const int*)d_in[4];
    float* out = (float*)d_out;
    float* ws  = (float*)d_ws;

    sparse_attn_slice<<<B * KVH * NSL, 256, 0, stream>>>(
        q, k_cache, v_cache, block_tables, context_lens, ws);
    sparse_attn_combine<<<B * H, 128, 0, stream>>>(ws, out);
}

// Round 10
// 47.973 us; speedup vs baseline: 1.3511x; 1.0568x over previous
//
#include <hip/hip_runtime.h>
#include <math.h>

constexpr int B = 16, H = 16, KVH = 4, D = 128;
constexpr int BLK = 16, MAXB = 256;
constexpr int GRP = H / KVH;     // 4 query heads per KV head
constexpr int NSL = 16;          // slices per (b,hkv); slice s owns union idx s, s+NSL, ...
constexpr int MAXCNT = 9;        // ceil(144/16)
constexpr int OSZ = GRP * D;     // 512
constexpr int WSTRIDE = OSZ + 2 * GRP;  // o[4][128], m[4], s[4] = 520 floats

// Layout closed form (validated R7/R9): head h attends kb iff pbid-kb<32 or kb%8==h%8.
// Group hkv: phases p..p+3, p=(hkv&1)*4. Union = strided [0,M) prefix-valid
// (kb=8*(i>>2)+p+(i&3), mask=1<<(i&3), kb strictly monotone) + local [M,pbid] (mask 15).

__global__ __launch_bounds__(256, 4) void sparse_attn_slice(
    const float* __restrict__ q,            // (B,H,D)
    const float* __restrict__ k_cache,      // (NB,KVH,32,16,4)
    const float* __restrict__ v_cache,      // (NB,KVH,128,16)
    const int* __restrict__ block_tables,   // (B,MAXB)
    const int* __restrict__ context_lens,   // (B,)
    float* __restrict__ ws)
{
    const int wg = blockIdx.x;
    const int gidx = wg >> 4, slice = wg & (NSL - 1);
    const int b = gidx >> 2, hkv = gidx & 3;
    const int tid = threadIdx.x;
    const int lane = tid & 63;
    const int wv = tid >> 6;                // 0..3

    const int q_pid = context_lens[b] - 1;
    const int pbid = q_pid >> 4;
    const int p = (hkv & 1) * 4;
    const int M = max(0, pbid - 31);        // strided region = [0, M)
    int nstr = 0;
    #pragma unroll
    for (int u = 0; u < 4; ++u) {
        const int dd = M - p - u;
        nstr += (dd > 0) ? ((dd + 7) >> 3) : 0;
    }
    const int U = nstr + (pbid - M + 1);
    const int cnt = (slice < U) ? ((U - 1 - slice) / NSL + 1) : 0;   // <= 9

    float* pb = ws + (size_t)wg * WSTRIDE;
    if (cnt == 0) {                         // must still write (ws poisoned)
        for (int i = tid; i < WSTRIDE; i += 256)
            pb[i] = (i >= OSZ && i < OSZ + GRP) ? -INFINITY : 0.f;
        return;
    }

    __shared__ float s_q[GRP * D];              // 2 KB
    __shared__ float s_p[GRP][MAXCNT * BLK];    // raw scores then probs
    __shared__ int   s_col[MAXCNT], s_msk[MAXCNT], s_bt[MAXCNT];
    __shared__ float s_m[GRP], s_s[GRP];
    __shared__ float s_o[4][OSZ];               // per-wave PV partials, 8 KB

    if (tid < 128)
        ((float4*)s_q)[tid] = ((const float4*)(q + (size_t)(b * H + hkv * GRP) * D))[tid];
    if (tid < cnt) {
        const int i = slice + tid * NSL;
        int kb, mk;
        if (i < nstr) { kb = ((i >> 2) << 3) + p + (i & 3); mk = 1 << (i & 3); }
        else          { kb = M + (i - nstr);                mk = 15; }
        s_col[tid] = kb;
        s_msk[tid] = mk;
        s_bt[tid]  = block_tables[b * MAXB + kb];
    }
    __syncthreads();

    const float sm_scale = 0.08838834764831845f; // 1/sqrt(128)
    const float4* q4 = (const float4*)s_q;

    // ---- scores: wave per block; 8 x 1KB contiguous loads per 8KB K block
    // f = lane + 64i -> d1 = (lane>>4) + 4i, n = lane&15
    {
        const int n = lane & 15;
        const int dg = lane >> 4;
        for (int j = wv; j < cnt; j += 4) {
            const float4* kp = (const float4*)(k_cache + (size_t)(s_bt[j] * KVH + hkv) * (D * BLK));
            float4 kb4[8];
            #pragma unroll
            for (int i = 0; i < 8; ++i) kb4[i] = kp[lane + 64 * i];
            float acc[GRP] = {0.f, 0.f, 0.f, 0.f};
            #pragma unroll
            for (int i = 0; i < 8; ++i) {
                const int d1 = dg + 4 * i;
                const float4 kv = kb4[i];
                #pragma unroll
                for (int g = 0; g < GRP; ++g) {
                    const float4 qv = q4[g * 32 + d1];
                    acc[g] += kv.x * qv.x + kv.y * qv.y + kv.z * qv.z + kv.w * qv.w;
                }
            }
            #pragma unroll
            for (int g = 0; g < GRP; ++g) {
                float a = acc[g];
                a += __shfl_xor(a, 16);
                a += __shfl_xor(a, 32);      // sum over the 4 dg groups
                if (dg == 0) s_p[g][j * 16 + n] = a * sm_scale;  // raw, unmasked
            }
        }
    }
    __syncthreads();

    // ---- softmax: wave g owns head g; mask (head-phase + causal), max, exp, sum
    {
        const int g = wv;
        const int tot = cnt * 16;
        float vals[3];
        float mx = -INFINITY;
        #pragma unroll
        for (int t = 0; t < 3; ++t) {
            const int e = lane + 64 * t;
            float v = -INFINITY;
            if (e < tot) {
                const int j = e >> 4, nn = e & 15;
                const int pos = s_col[j] * BLK + nn;
                if (((s_msk[j] >> g) & 1) && pos <= q_pid) v = s_p[g][e];
            }
            vals[t] = v;
            mx = fmaxf(mx, v);
        }
        #pragma unroll
        for (int off = 1; off < 64; off <<= 1)
            mx = fmaxf(mx, __shfl_xor(mx, off));
        float sum = 0.f;
        #pragma unroll
        for (int t = 0; t < 3; ++t) {
            const int e = lane + 64 * t;
            const float pe = (vals[t] == -INFINITY) ? 0.f : __expf(vals[t] - mx);
            sum += pe;
            if (e < tot) s_p[g][e] = pe;
        }
        #pragma unroll
        for (int off = 1; off < 64; off <<= 1)
            sum += __shfl_xor(sum, off);
        if (lane == 0) { s_m[g] = mx; s_s[g] = sum; }
    }
    __syncthreads();

    // ---- PV: wave per block; 8 x 1KB contiguous loads per 8KB V block
    // f = lane + 64i -> d = (lane>>2) + 16i, token group ng = lane&3 (tokens 4ng..4ng+3)
    {
        const int ng = lane & 3;
        float o[8][GRP];
        #pragma unroll
        for (int i = 0; i < 8; ++i)
            #pragma unroll
            for (int g = 0; g < GRP; ++g) o[i][g] = 0.f;

        for (int j = wv; j < cnt; j += 4) {
            const float4* vp = (const float4*)(v_cache + (size_t)(s_bt[j] * KVH + hkv) * (D * BLK));
            float4 vb4[8];
            #pragma unroll
            for (int i = 0; i < 8; ++i) vb4[i] = vp[lane + 64 * i];
            float4 pw[GRP];
            #pragma unroll
            for (int g = 0; g < GRP; ++g)
                pw[g] = ((const float4*)&s_p[g][j * 16])[ng];
            #pragma unroll
            for (int i = 0; i < 8; ++i) {
                #pragma unroll
                for (int g = 0; g < GRP; ++g)
                    o[i][g] += vb4[i].x * pw[g].x + vb4[i].y * pw[g].y
                             + vb4[i].z * pw[g].z + vb4[i].w * pw[g].w;
            }
        }
        // token-sum across the 4 ng lanes; then write distinct dims from ng==0
        #pragma unroll
        for (int i = 0; i < 8; ++i) {
            #pragma unroll
            for (int g = 0; g < GRP; ++g) {
                float v = o[i][g];
                v += __shfl_xor(v, 1);
                v += __shfl_xor(v, 2);
                o[i][g] = v;
            }
        }
        if (ng == 0) {
            const int k = lane >> 2;        // 0..15
            #pragma unroll
            for (int i = 0; i < 8; ++i)
                #pragma unroll
                for (int g = 0; g < GRP; ++g)
                    s_o[wv][g * D + k + 16 * i] = o[i][g];
        }
    }
    __syncthreads();

    // ---- merge 4 wave-partials (plain add; softmax stats are WG-global) + write
    {
        const int f = tid * 2;
        const float r0 = s_o[0][f] + s_o[1][f] + s_o[2][f] + s_o[3][f];
        const float r1 = s_o[0][f+1] + s_o[1][f+1] + s_o[2][f+1] + s_o[3][f+1];
        ((float2*)pb)[tid] = make_float2(r0, r1);
        if (tid < GRP) {
            pb[OSZ + tid]       = s_m[tid];
            pb[OSZ + GRP + tid] = s_s[tid];
        }
    }
}

// ---------------- combine: LSE-merge NSL slices per (b,h) ----------------
__global__ __launch_bounds__(128) void sparse_attn_combine(
    const float* __restrict__ ws,
    float* __restrict__ out)
{
    const int bh = blockIdx.x;              // b*H + h
    const int h = bh & (H - 1), b = bh >> 4;
    const int gidx = b * KVH + (h >> 2);
    const int g = h & 3;
    const int d = threadIdx.x;

    const float* base = ws + (size_t)(gidx * NSL) * WSTRIDE;

    float m = -INFINITY;
    #pragma unroll
    for (int e = 0; e < NSL; ++e)
        m = fmaxf(m, base[e * WSTRIDE + OSZ + g]);

    float num = 0.f, den = 0.f;
    #pragma unroll
    for (int e = 0; e < NSL; ++e) {
        const float ms = base[e * WSTRIDE + OSZ + g];
        const float ss = base[e * WSTRIDE + OSZ + GRP + g];
        const float a = (ms == -INFINITY) ? 0.f : __expf(ms - m);
        num += base[e * WSTRIDE + g * D + d] * a;
        den += ss * a;
    }
    out[bh * D + d] = num / den;
}

extern "C" void kernel_launch(void* const* d_in, const int* in_sizes, int n_in,
                              void* d_out, int out_size, void* d_ws, size_t ws_size,
                              hipStream_t stream) {
    const float* q            = (const float*)d_in[0];
    const float* k_cache      = (const float*)d_in[1];
    const float* v_cache      = (const float*)d_in[2];
    const int*   block_tables = (const int*)d_in[3];
    const int*   context_lens = (const int*)d_in[4];
    float* out = (float*)d_out;
    float* ws  = (float*)d_ws;

    sparse_attn_slice<<<B * KVH * NSL, 256, 0, stream>>>(
        q, k_cache, v_cache, block_tables, context_lens, ws);
    sparse_attn_combine<<<B * H, 128, 0, stream>>>(ws, out);
}

// Round 11
// 26.859 us; speedup vs baseline: 2.4132x; 1.7861x over previous
//
#include <hip/hip_runtime.h>
#include <math.h>

constexpr int B = 16, H = 16, KVH = 4, D = 128;
constexpr int BLK = 16, MAXB = 256;
constexpr int GRP = H / KVH;     // 4 query heads per KV head
constexpr int NSL = 16;          // slices per (b,hkv); slice s owns union idx s, s+NSL, ...
constexpr int MAXCNT = 9;        // ceil(144/16)
constexpr int WSTRIDE = D + 2;   // per-(slice,head) partial: o[128], m, s

// Layout closed form (validated R7/R9/R10): head h attends kb iff pbid-kb<32 or kb%8==h%8.
// Group hkv: phases p..p+3, p=(hkv&1)*4. Union = strided [0,M) prefix-valid
// (kb=8*(i>>2)+p+(i&3), mask=1<<(i&3), kb strictly monotone) + local [M,pbid] (mask 15).

__global__ __launch_bounds__(256) void sparse_attn_slice(
    const float* __restrict__ q,            // (B,H,D)
    const float* __restrict__ k_cache,      // (NB,KVH,32,16,4)
    const float* __restrict__ v_cache,      // (NB,KVH,128,16)
    const int* __restrict__ block_tables,   // (B,MAXB)
    const int* __restrict__ context_lens,   // (B,)
    float* __restrict__ wsB)
{
    const int wg = blockIdx.x;
    const int gidx = wg >> 4, slice = wg & (NSL - 1);
    const int b = gidx >> 2, hkv = gidx & 3;
    const int tid = threadIdx.x;
    const int lane = tid & 63;
    const int wv = tid >> 6;                // 0..3

    const int q_pid = context_lens[b] - 1;
    const int pbid = q_pid >> 4;
    const int p = (hkv & 1) * 4;
    const int M = max(0, pbid - 31);        // strided region = [0, M)
    int nstr = 0;
    #pragma unroll
    for (int u = 0; u < 4; ++u) {
        const int dd = M - p - u;
        nstr += (dd > 0) ? ((dd + 7) >> 3) : 0;
    }
    const int U = nstr + (pbid - M + 1);
    const int cnt = (slice < U) ? ((U - 1 - slice) / NSL + 1) : 0;   // <= 9

    float* pb = wsB + (size_t)((gidx * NSL + slice) * GRP) * WSTRIDE;
    if (cnt == 0) {                         // must still write (ws poisoned)
        for (int i = tid; i < GRP * WSTRIDE; i += 256)
            pb[i] = ((i % WSTRIDE) == D) ? -INFINITY : 0.f;
        return;
    }

    __shared__ float s_q[GRP * D];              // 2 KB
    __shared__ float s_p[GRP][MAXCNT * BLK];    // raw(masked) scores then probs
    __shared__ int   s_col[MAXCNT], s_msk[MAXCNT], s_bt[MAXCNT];
    __shared__ float s_redm[GRP][4];
    __shared__ float s_m[GRP], s_s[GRP];

    if (tid < 128)
        ((float4*)s_q)[tid] = ((const float4*)(q + (size_t)(b * H + hkv * GRP) * D))[tid];
    if (tid < MAXCNT) {
        const int i = min(slice + tid * NSL, U - 1);   // clamped: always a valid entry
        int kb, mk;
        if (i < nstr) { kb = ((i >> 2) << 3) + p + (i & 3); mk = 1 << (i & 3); }
        else          { kb = M + (i - nstr);                mk = 15; }
        s_col[tid] = kb;
        s_msk[tid] = (tid < cnt) ? mk : 0;
        s_bt[tid]  = block_tables[b * MAXB + kb];
    }
    __syncthreads();

    const float sm_scale = 0.08838834764831845f; // 1/sqrt(128)
    const float4* q4 = (const float4*)s_q;

    // ---- scores (R5-verbatim): wave per block; lane = (n, dq); 8 float4 per lane
    const int n  = (lane >> 2) & 15;
    const int dq = lane & 3;
    {
        float mx[GRP] = {-INFINITY, -INFINITY, -INFINITY, -INFINITY};
        for (int j = wv; j < cnt; j += 4) {
            const int pos = s_col[j] * BLK + n;  // uniform across the dq-quad
            float sc[GRP];
            if (pos <= q_pid) {
                const float4* kp = (const float4*)(k_cache + (size_t)(s_bt[j] * KVH + hkv) * (D * BLK));
                float acc[GRP] = {0.f, 0.f, 0.f, 0.f};
                #pragma unroll
                for (int i = 0; i < 8; ++i) {
                    const int d1 = dq * 8 + i;
                    const float4 kv = kp[d1 * 16 + n];
                    #pragma unroll
                    for (int g = 0; g < GRP; ++g) {
                        const float4 qv = q4[g * 32 + d1];
                        acc[g] += kv.x * qv.x + kv.y * qv.y + kv.z * qv.z + kv.w * qv.w;
                    }
                }
                const int mk = s_msk[j];
                #pragma unroll
                for (int g = 0; g < GRP; ++g) {
                    float a = acc[g];
                    a += __shfl_xor(a, 1);
                    a += __shfl_xor(a, 2);   // full dot on all 4 dq lanes
                    sc[g] = ((mk >> g) & 1) ? a * sm_scale : -INFINITY;
                }
            } else {
                #pragma unroll
                for (int g = 0; g < GRP; ++g) sc[g] = -INFINITY;
            }
            if (dq == 0) {
                #pragma unroll
                for (int g = 0; g < GRP; ++g) s_p[g][j * 16 + n] = sc[g];
            }
            #pragma unroll
            for (int g = 0; g < GRP; ++g) mx[g] = fmaxf(mx[g], sc[g]);
        }
        #pragma unroll
        for (int g = 0; g < GRP; ++g) {
            float v = mx[g];
            #pragma unroll
            for (int off = 1; off < 64; off <<= 1)
                v = fmaxf(v, __shfl_xor(v, off));
            if (lane == 0) s_redm[g][wv] = v;
        }
    }

    // ---- V prefetch: ALL V loads issued now, unconditionally (clamped index).
    // Thread owns d = tid/2, token half dh = tid&1 (tokens dh*8..dh*8+7).
    float4 vr0[MAXCNT], vr1[MAXCNT];
    #pragma unroll
    for (int jj = 0; jj < MAXCNT; ++jj) {
        const int jc = (jj < cnt) ? jj : cnt - 1;    // safe dup of last block
        const float4* vp = (const float4*)(v_cache + (size_t)(s_bt[jc] * KVH + hkv) * (D * BLK));
        vr0[jj] = vp[tid * 2];
        vr1[jj] = vp[tid * 2 + 1];
    }
    __syncthreads();   // drains all 18 in-flight V loads + publishes s_p/s_redm

    // ---- softmax: wave g owns head g; zero-pad probs to MAXCNT*BLK
    {
        const int g = wv;
        const int tot = cnt * BLK;
        const float mg = fmaxf(fmaxf(s_redm[g][0], s_redm[g][1]),
                               fmaxf(s_redm[g][2], s_redm[g][3]));
        float sum = 0.f;
        #pragma unroll
        for (int t = 0; t < 3; ++t) {       // 3*64 = 192 >= 144
            const int e = lane + 64 * t;
            float pe = 0.f;
            if (e < tot) {
                const float v = s_p[g][e];
                pe = (v == -INFINITY) ? 0.f : __expf(v - mg);
            }
            if (e < MAXCNT * BLK) s_p[g][e] = pe;
            sum += pe;
        }
        #pragma unroll
        for (int off = 1; off < 64; off <<= 1)
            sum += __shfl_xor(sum, off);
        if (lane == 0) { s_m[g] = mg; s_s[g] = sum; }
    }
    __syncthreads();

    // ---- PV: pure FMA, fully unrolled; probs are zero for jj >= cnt
    {
        const int dh = tid & 1;
        float acc[GRP] = {0.f, 0.f, 0.f, 0.f};
        #pragma unroll
        for (int jj = 0; jj < MAXCNT; ++jj) {
            const float4 v0 = vr0[jj], v1 = vr1[jj];
            #pragma unroll
            for (int g = 0; g < GRP; ++g) {
                const float4 p0 = ((const float4*)&s_p[g][jj * BLK])[dh * 2];
                const float4 p1 = ((const float4*)&s_p[g][jj * BLK])[dh * 2 + 1];
                acc[g] += v0.x * p0.x + v0.y * p0.y + v0.z * p0.z + v0.w * p0.w
                        + v1.x * p1.x + v1.y * p1.y + v1.z * p1.z + v1.w * p1.w;
            }
        }
        #pragma unroll
        for (int g = 0; g < GRP; ++g)
            acc[g] += __shfl_xor(acc[g], 1);
        if (dh == 0) {
            #pragma unroll
            for (int g = 0; g < GRP; ++g)
                pb[g * WSTRIDE + (tid >> 1)] = acc[g];
        }
        if (tid == 0) {
            #pragma unroll
            for (int g = 0; g < GRP; ++g) {
                pb[g * WSTRIDE + D]     = s_m[g];
                pb[g * WSTRIDE + D + 1] = s_s[g];
            }
        }
    }
}

// ---------------- combine: LSE-merge NSL slices per (b,h) ----------------
__global__ __launch_bounds__(128) void sparse_attn_combine(
    const float* __restrict__ wsB,
    float* __restrict__ out)
{
    const int bh = blockIdx.x;              // b*H + h
    const int h = bh & (H - 1);
    const int gidx = (bh >> 4) * 4 + (h >> 2);
    const int g = h & 3;
    const int d = threadIdx.x;

    const float* base = wsB + (size_t)(gidx * NSL * GRP + g) * WSTRIDE;

    float m = -INFINITY;
    #pragma unroll
    for (int s = 0; s < NSL; ++s)
        m = fmaxf(m, base[s * GRP * WSTRIDE + D]);

    float num = 0.f, den = 0.f;
    #pragma unroll
    for (int s = 0; s < NSL; ++s) {
        const float ms = base[s * GRP * WSTRIDE + D];
        const float ss = base[s * GRP * WSTRIDE + D + 1];
        const float a = (ms == -INFINITY) ? 0.f : __expf(ms - m);
        num += base[s * GRP * WSTRIDE + d] * a;
        den += ss * a;
    }
    out[bh * D + d] = num / den;
}

extern "C" void kernel_launch(void* const* d_in, const int* in_sizes, int n_in,
                              void* d_out, int out_size, void* d_ws, size_t ws_size,
                              hipStream_t stream) {
    const float* q            = (const float*)d_in[0];
    const float* k_cache      = (const float*)d_in[1];
    const float* v_cache      = (const float*)d_in[2];
    const int*   block_tables = (const int*)d_in[3];
    const int*   context_lens = (const int*)d_in[4];
    float* out = (float*)d_out;
    float* wsB = (float*)d_ws;

    sparse_attn_slice<<<B * KVH * NSL, 256, 0, stream>>>(
        q, k_cache, v_cache, block_tables, context_lens, wsB);
    sparse_attn_combine<<<B * H, 128, 0, stream>>>(wsB, out);
}